// Round 5
// baseline (116.826 us; speedup 1.0000x reference)
//
#include <hip/hip_runtime.h>

// LRNN: h_t = g_t*h_{t-1} + (1-g_t)*x_t along W, (B,H,W,C)=(8,256,256,64) f32.
// R4: explicit two-pass chunked scan with float4 vectorization.
// R3 post-mortem: VGPR=28 proved the compiler de-registered the 32-float
// hl[]/ap[] state (spill or remat) -> pass B became a serial memory phase.
// New structure keeps per-thread state at ~12 floats so nothing CAN spill:
//   pass A: scan chunk keeping only (gate-product a[4], local end h[4])
//   LDS carry exchange + per-thread compose of incoming state hin[4]
//   pass B: RE-READ x,g (L2/LLC-hot) and rerun true recurrence from hin.
// float4 everywhere: 16 B/lane loads/stores, 1 KB/wave per instruction.
// 512-thread blocks (2 rows), 1024 blocks, launch_bounds(512,8) -> 32 waves/CU.

#define LRNN_W 256
#define LRNN_C 64
#define C4 (LRNN_C / 4)   // 16 float4 per w-position
#define CHUNK 16
#define NCH 16            // W / CHUNK
#define ROWS_PER_BLK 2

__global__ __launch_bounds__(512, 8) void lrnn_scan_kernel(
    const float4* __restrict__ X4, const float4* __restrict__ G4,
    float4* __restrict__ out4) {
    __shared__ float4 lA[ROWS_PER_BLK][NCH][C4];  // per-chunk gate product
    __shared__ float4 lB[ROWS_PER_BLK][NCH][C4];  // per-chunk local end state

    const int c4 = threadIdx.x & (C4 - 1);         // 0..15 (4 channels)
    const int k  = (threadIdx.x >> 4) & (NCH - 1); // chunk 0..15
    const int r  = threadIdx.x >> 8;               // row-in-block 0..1
    const int row = blockIdx.x * ROWS_PER_BLK + r; // 0..2047
    // float4 index; max = 2047*4096 + 15*256 + 15 < 2^23
    const int b4 = row * (LRNN_W * C4) + k * (CHUNK * C4) + c4;

    // ---- Pass A: local scan, keep only (a, h) ----
    float h0 = 0.f, h1 = 0.f, h2 = 0.f, h3 = 0.f;
    float a0 = 1.f, a1 = 1.f, a2 = 1.f, a3 = 1.f;
#pragma unroll
    for (int t = 0; t < CHUNK; ++t) {
        const float4 x = X4[b4 + t * C4];
        const float4 g = G4[b4 + t * C4];
        h0 = fmaf(g.x, h0 - x.x, x.x); a0 *= g.x;
        h1 = fmaf(g.y, h1 - x.y, x.y); a1 *= g.y;
        h2 = fmaf(g.z, h2 - x.z, x.z); a2 *= g.z;
        h3 = fmaf(g.w, h3 - x.w, x.w); a3 *= g.w;
    }

    lA[r][k][c4] = make_float4(a0, a1, a2, a3);
    lB[r][k][c4] = make_float4(h0, h1, h2, h3);
    __syncthreads();

    // ---- Compose incoming state: fold chunks 0..k-1 in order ----
    float i0 = 0.f, i1 = 0.f, i2 = 0.f, i3 = 0.f;
    for (int j = 0; j < k; ++j) {
        const float4 A = lA[r][j][c4];
        const float4 Bv = lB[r][j][c4];
        i0 = fmaf(A.x, i0, Bv.x);
        i1 = fmaf(A.y, i1, Bv.y);
        i2 = fmaf(A.z, i2, Bv.z);
        i3 = fmaf(A.w, i3, Bv.w);
    }

    // ---- Pass B: re-read (L2/LLC-hot), rerun true recurrence, store ----
#pragma unroll
    for (int t = 0; t < CHUNK; ++t) {
        const float4 x = X4[b4 + t * C4];
        const float4 g = G4[b4 + t * C4];
        i0 = fmaf(g.x, i0 - x.x, x.x);
        i1 = fmaf(g.y, i1 - x.y, x.y);
        i2 = fmaf(g.z, i2 - x.z, x.z);
        i3 = fmaf(g.w, i3 - x.w, x.w);
        out4[b4 + t * C4] = make_float4(i0, i1, i2, i3);
    }
}

extern "C" void kernel_launch(void* const* d_in, const int* in_sizes, int n_in,
                              void* d_out, int out_size, void* d_ws, size_t ws_size,
                              hipStream_t stream) {
    const float4* X4 = (const float4*)d_in[0];
    const float4* G4 = (const float4*)d_in[1];
    float4* out4 = (float4*)d_out;

    const int rows = 8 * 256;                 // B*H = 2048
    const int grid = rows / ROWS_PER_BLK;     // 1024 blocks
    lrnn_scan_kernel<<<grid, 512, 0, stream>>>(X4, G4, out4);
}

// Round 6
// 62.618 us; speedup vs baseline: 1.8657x; 1.8657x over previous
//
#include <hip/hip_runtime.h>

// LRNN: h_t = g_t*h_{t-1} + (1-g_t)*x_t along W, (B,H,W,C)=(8,256,256,64) f32.
// R5 = R3 (best per-byte structure: single read, chunked scan, LDS carry
// exchange, per-thread state parked in AGPRs) + NONTEMPORAL STORES.
// Theory: all variants plateau at ~3.3 TB/s effective despite ample in-flight
// concurrency; the out-stream's write-allocate churns the 256MB Infinity
// Cache whose capacity exactly equals X+G. NT stores keep the output from
// evicting X+G, so replays serve reads from LLC and writes stream to HBM.

#define LRNN_W 256
#define LRNN_C 64
#define CHUNK 16
#define NCHUNK 16  // LRNN_W / CHUNK

__global__ __launch_bounds__(1024, 8) void lrnn_scan_kernel(
    const float* __restrict__ X, const float* __restrict__ G,
    float* __restrict__ out) {
    __shared__ float lA[NCHUNK][LRNN_C];  // per-chunk gate product
    __shared__ float lB[NCHUNK][LRNN_C];  // per-chunk local end state

    const int c = threadIdx.x & (LRNN_C - 1);
    const int k = threadIdx.x >> 6;        // chunk index = wave index, 0..15
    const int row = blockIdx.x;            // 0..2047  (b*H + h)
    const int base = row * (LRNN_W * LRNN_C) + k * (CHUNK * LRNN_C) + c;

    // Pass A: local scan of the chunk (h_in = 0) + running gate product.
    // h_t = hl[t] + ap[t] * h_in for the true incoming state h_in.
    float hl[CHUNK], ap[CHUNK];
    float h = 0.0f, a = 1.0f;
#pragma unroll
    for (int t = 0; t < CHUNK; ++t) {
        const float x = X[base + t * LRNN_C];
        const float g = G[base + t * LRNN_C];
        h = fmaf(g, h - x, x);  // g*h + (1-g)*x
        a *= g;
        hl[t] = h;
        ap[t] = a;
    }

    // Carry exchange: (A_k, B_k) per (chunk, channel).
    lA[k][c] = a;
    lB[k][c] = h;
    __syncthreads();

    // Compose incoming state for this chunk: fold chunks 0..k-1 in order.
    // k is wave-uniform (chunk == wave) -> no divergence; lanes read
    // consecutive c -> conflict-free LDS.
    float hin = 0.0f;
    for (int j = 0; j < k; ++j)
        hin = fmaf(lA[j][c], hin, lB[j][c]);

    // Pass B: fixup + nontemporal store (don't write-allocate the LLC).
#pragma unroll
    for (int t = 0; t < CHUNK; ++t)
        __builtin_nontemporal_store(fmaf(ap[t], hin, hl[t]),
                                    &out[base + t * LRNN_C]);
}

extern "C" void kernel_launch(void* const* d_in, const int* in_sizes, int n_in,
                              void* d_out, int out_size, void* d_ws, size_t ws_size,
                              hipStream_t stream) {
    const float* X = (const float*)d_in[0];
    const float* G = (const float*)d_in[1];
    float* out = (float*)d_out;

    const int rows = 8 * 256;  // B*H = 2048 blocks, one row per block
    lrnn_scan_kernel<<<rows, NCHUNK * LRNN_C, 0, stream>>>(X, G, out);
}